// Round 1
// baseline (2585.282 us; speedup 1.0000x reference)
//
#include <hip/hip_runtime.h>

#define D_DIM 128
#define N_ENT 100000
#define R_REL 8
#define E_EDGE 131072
#define B_HEAD 32768

// Transpose rel_W [r][i][o] -> relT [r][o][i] so GEMMs read the dot axis contiguously.
__global__ __launch_bounds__(256) void transpose_relW(const float* __restrict__ relW,
                                                      float* __restrict__ relT) {
  __shared__ float t[32][33];
  int r = blockIdx.y;
  int i0 = (blockIdx.x >> 2) * 32;
  int o0 = (blockIdx.x & 3) * 32;
  int tx = threadIdx.x & 31, ty = threadIdx.x >> 5;
  const float* src = relW + (size_t)r * D_DIM * D_DIM;
  float* dst = relT + (size_t)r * D_DIM * D_DIM;
#pragma unroll
  for (int k = 0; k < 32; k += 8) t[ty + k][tx] = src[(i0 + ty + k) * D_DIM + o0 + tx];
  __syncthreads();
#pragma unroll
  for (int k = 0; k < 32; k += 8) dst[(o0 + ty + k) * D_DIM + i0 + tx] = t[tx][ty + k];
}

__global__ __launch_bounds__(256) void zero_f4(float4* __restrict__ p) {
  p[(size_t)blockIdx.x * 256 + threadIdx.x] = make_float4(0.f, 0.f, 0.f, 0.f);
}

// One edge handled by 32 lanes (128 floats). agg[rl][row][:] += w * tail[col][:]
__global__ __launch_bounds__(256) void edge_scatter(const float* __restrict__ tail,
                                                    const float* __restrict__ ew,
                                                    const int* __restrict__ erow,
                                                    const int* __restrict__ ecol,
                                                    float* __restrict__ agg) {
  int rl = blockIdx.y;
  int e = blockIdx.x * 8 + (threadIdx.x >> 5);
  int lane = threadIdx.x & 31;
  size_t roff = (size_t)rl * E_EDGE + e;
  float w = ew[roff];
  int row = erow[roff];
  int col = ecol[roff];
  float4 t = ((const float4*)(tail + (size_t)col * D_DIM))[lane];
  float* dst = agg + ((size_t)rl * B_HEAD + row) * D_DIM + lane * 4;
  atomicAdd(dst + 0, w * t.x);
  atomicAdd(dst + 1, w * t.y);
  atomicAdd(dst + 2, w * t.z);
  atomicAdd(dst + 3, w * t.w);
}

// out[n][o] = sum_i A[n][i] * Wm[o][i].  Wm is [o][i] (128x128).
// 32-row tile per block, 256 threads, thread tile 4 rows x 4 cols (cols o = lane_o + 32j).
// W staged in two 64-o halves, XOR-swizzled float4 layout: slot = i4 ^ (o&31)
// -> conflict-free staging writes AND main-loop reads. LDS ~49KB -> 3 blocks/CU.
template <bool SCATTER>
__global__ __launch_bounds__(256) void gemm_tile(const float* __restrict__ Abase,
                                                 const float* __restrict__ Wbase,
                                                 const int* __restrict__ headBase,
                                                 float* __restrict__ out) {
  __shared__ float wsw[64 * D_DIM];
  __shared__ float As[32 * 132];
  int tid = threadIdx.x;
  const float* A;
  const float* Wm;
  const int* head = nullptr;
  if (SCATTER) {
    int rl = blockIdx.y;
    A = Abase + (size_t)rl * B_HEAD * D_DIM;
    Wm = Wbase + (size_t)rl * D_DIM * D_DIM;
    head = headBase + (size_t)rl * B_HEAD;
  } else {
    A = Abase;
    Wm = Wbase;
  }
  int rowbase = blockIdx.x * 32;
  float4* wsw4 = (float4*)wsw;
  float4* As4 = (float4*)As;
  int lane_o = tid & 31;
  int row0 = (tid >> 5) << 2;
  float acc[4][4] = {};

  // stage A tile: 32 rows x 128 (stride 132 floats = 33 float4s, conflict-free)
  {
    const float4* A4 = (const float4*)A;
#pragma unroll
    for (int j = 0; j < 4; ++j) {
      int e4 = tid + j * 256;
      int n = e4 >> 5, i4 = e4 & 31;
      As4[n * 33 + i4] = A4[((size_t)(rowbase + n) << 5) + i4];
    }
  }

  for (int h = 0; h < 2; ++h) {
    const float4* W4 = (const float4*)(Wm + (size_t)(64 * h) * D_DIM);
#pragma unroll
    for (int j = 0; j < 8; ++j) {
      int e4 = tid + j * 256;  // 2048 float4 = 64 o x 32 chunks
      int o = e4 >> 5, i4 = e4 & 31;
      wsw4[(o << 5) + ((i4 ^ o) & 31)] = W4[e4];
    }
    __syncthreads();
#pragma unroll
    for (int i4 = 0; i4 < 32; ++i4) {
      float4 wv[2], av[4];
#pragma unroll
      for (int c = 0; c < 2; ++c) {
        int o = lane_o + 32 * c;
        wv[c] = wsw4[(o << 5) + ((i4 ^ o) & 31)];
      }
#pragma unroll
      for (int r = 0; r < 4; ++r) av[r] = As4[(row0 + r) * 33 + i4];
#pragma unroll
      for (int r = 0; r < 4; ++r)
#pragma unroll
        for (int c = 0; c < 2; ++c) {
          acc[r][2 * h + c] += av[r].x * wv[c].x + av[r].y * wv[c].y +
                               av[r].z * wv[c].z + av[r].w * wv[c].w;
        }
    }
    __syncthreads();
  }

  // acc[r][j] corresponds to col o = lane_o + 32*j  (j = 2h+c: 0,+32,+64,+96)
#pragma unroll
  for (int r = 0; r < 4; ++r) {
    int lr = rowbase + row0 + r;
    if (SCATTER) {
      float* orow = out + (size_t)head[lr] * D_DIM;
#pragma unroll
      for (int j = 0; j < 4; ++j) atomicAdd(orow + lane_o + 32 * j, acc[r][j]);
    } else {
      float* orow = out + (size_t)lr * D_DIM;
#pragma unroll
      for (int j = 0; j < 4; ++j) orow[lane_o + 32 * j] = acc[r][j];
    }
  }
}

__global__ __launch_bounds__(256) void relu_k(float* __restrict__ out) {
  size_t i = ((size_t)blockIdx.x * 256 + threadIdx.x) * 4;
  float4* p = (float4*)(out + i);
  float4 v = *p;
  v.x = fmaxf(v.x, 0.f);
  v.y = fmaxf(v.y, 0.f);
  v.z = fmaxf(v.z, 0.f);
  v.w = fmaxf(v.w, 0.f);
  *p = v;
}

extern "C" void kernel_launch(void* const* d_in, const int* in_sizes, int n_in,
                              void* d_out, int out_size, void* d_ws, size_t ws_size,
                              hipStream_t stream) {
  const float* x = (const float*)d_in[0];
  const float* tail = (const float*)d_in[1];
  const float* W = (const float*)d_in[2];
  const float* relW = (const float*)d_in[3];
  const float* ew = (const float*)d_in[4];
  const int* erow = (const int*)d_in[5];
  const int* ecol = (const int*)d_in[6];
  const int* head = (const int*)d_in[7];
  float* out = (float*)d_out;

  // ws layout: [relT: R*128*128 f32 = 512KB][agg: chunk * B*128 f32 (16.78MB each)]
  float* relT = (float*)d_ws;
  size_t relT_bytes = (size_t)R_REL * D_DIM * D_DIM * sizeof(float);
  float* agg = (float*)((char*)d_ws + relT_bytes);
  size_t per_rel = (size_t)B_HEAD * D_DIM * sizeof(float);
  size_t avail = (ws_size > relT_bytes) ? (ws_size - relT_bytes) : 0;
  int chunk = (int)(avail / per_rel);
  if (chunk > R_REL) chunk = R_REL;
  if (chunk < 1) chunk = 1;

  transpose_relW<<<dim3(16, R_REL), 256, 0, stream>>>(relW, relT);

  // emb_all = x @ W.T  (full overwrite of d_out)
  gemm_tile<false><<<dim3(N_ENT / 32, 1), 256, 0, stream>>>(x, W, nullptr, out);

  for (int r0 = 0; r0 < R_REL; r0 += chunk) {
    int c = (R_REL - r0 < chunk) ? (R_REL - r0) : chunk;
    zero_f4<<<dim3(c * (B_HEAD * D_DIM / 4 / 256)), 256, 0, stream>>>((float4*)agg);
    edge_scatter<<<dim3(E_EDGE / 8, c), 256, 0, stream>>>(
        tail, ew + (size_t)r0 * E_EDGE, erow + (size_t)r0 * E_EDGE,
        ecol + (size_t)r0 * E_EDGE, agg);
    gemm_tile<true><<<dim3(B_HEAD / 32, c), 256, 0, stream>>>(
        agg, relT + (size_t)r0 * D_DIM * D_DIM, head + (size_t)r0 * B_HEAD, out);
  }

  relu_k<<<dim3(N_ENT * D_DIM / 4 / 256), 256, 0, stream>>>(out);
}

// Round 2
// 1198.768 us; speedup vs baseline: 2.1566x; 2.1566x over previous
//
#include <hip/hip_runtime.h>

#define D_DIM 128
#define N_ENT 100000
#define R_REL 8
#define E_EDGE 131072
#define B_HEAD 32768
#define NH_PAD 100352  // 1024*98 >= N_ENT

__device__ inline void f4fma(float4& acc, float w, const float4& v) {
  acc.x += w * v.x; acc.y += w * v.y; acc.z += w * v.z; acc.w += w * v.w;
}

// ---------- CSR build ----------
__global__ __launch_bounds__(256) void zero_counts(int* __restrict__ p) {
  p[blockIdx.x * 256 + threadIdx.x] = 0;  // exact grid
}

__global__ __launch_bounds__(256) void hist_edges(const int* __restrict__ erow,
                                                  int* __restrict__ cnt) {
  int r = blockIdx.y;
  int e = blockIdx.x * 256 + threadIdx.x;
  int row = erow[(size_t)r * E_EDGE + e];
  atomicAdd(cnt + r * B_HEAD + row, 1);
}

__global__ __launch_bounds__(256) void hist_heads(const int* __restrict__ head,
                                                  int* __restrict__ cnt) {
  int i = blockIdx.x * 256 + threadIdx.x;  // < R*B
  atomicAdd(cnt + head[i], 1);
}

// exclusive scan of cnt[r*B..] -> cur[r*B..] with base r*E (one block per relation)
__global__ __launch_bounds__(1024) void scan_rel(const int* __restrict__ cnt,
                                                 int* __restrict__ cur) {
  int r = blockIdx.x, t = threadIdx.x;
  const int* c = cnt + (size_t)r * B_HEAD;
  int* q = cur + (size_t)r * B_HEAD;
  int base = t * 32;
  int s = 0;
#pragma unroll
  for (int k = 0; k < 32; ++k) s += c[base + k];
  __shared__ int ps[1024];
  ps[t] = s;
  __syncthreads();
  for (int off = 1; off < 1024; off <<= 1) {
    int v = (t >= off) ? ps[t - off] : 0;
    __syncthreads();
    ps[t] += v;
    __syncthreads();
  }
  int g = r * E_EDGE + ps[t] - s;
  for (int k = 0; k < 32; ++k) {
    q[base + k] = g;
    g += c[base + k];
  }
}

__global__ __launch_bounds__(1024) void scan_heads(const int* __restrict__ cnt,
                                                   int* __restrict__ cur) {
  int t = threadIdx.x;
  int base = t * 98;
  int s = 0;
  for (int k = 0; k < 98; ++k) {
    int i = base + k;
    if (i < N_ENT) s += cnt[i];
  }
  __shared__ int ps[1024];
  ps[t] = s;
  __syncthreads();
  for (int off = 1; off < 1024; off <<= 1) {
    int v = (t >= off) ? ps[t - off] : 0;
    __syncthreads();
    ps[t] += v;
    __syncthreads();
  }
  int g = ps[t] - s;
  for (int k = 0; k < 98; ++k) {
    int i = base + k;
    if (i < N_ENT) {
      cur[i] = g;
      g += cnt[i];
    }
  }
}

__global__ __launch_bounds__(256) void scatter_edges(const int* __restrict__ erow,
                                                     const int* __restrict__ ecol,
                                                     const float* __restrict__ ew,
                                                     int* __restrict__ cur,
                                                     int* __restrict__ sCol,
                                                     float* __restrict__ sW) {
  int r = blockIdx.y;
  int e = blockIdx.x * 256 + threadIdx.x;
  size_t idx = (size_t)r * E_EDGE + e;
  int row = erow[idx];
  int pos = atomicAdd(cur + r * B_HEAD + row, 1);
  sCol[pos] = ecol[idx];
  sW[pos] = ew[idx];
}

__global__ __launch_bounds__(256) void scatter_heads(const int* __restrict__ head,
                                                     int* __restrict__ cur,
                                                     int* __restrict__ list) {
  int i = blockIdx.x * 256 + threadIdx.x;  // flat (r,row) id
  int pos = atomicAdd(cur + head[i], 1);
  list[pos] = i;
}

// ---------- GEMMs ----------
// Transpose rel_W [r][i][o] -> relT [r][o][i]
__global__ __launch_bounds__(256) void transpose_relW(const float* __restrict__ relW,
                                                      float* __restrict__ relT) {
  __shared__ float t[32][33];
  int r = blockIdx.y;
  int i0 = (blockIdx.x >> 2) * 32;
  int o0 = (blockIdx.x & 3) * 32;
  int tx = threadIdx.x & 31, ty = threadIdx.x >> 5;
  const float* src = relW + (size_t)r * D_DIM * D_DIM;
  float* dst = relT + (size_t)r * D_DIM * D_DIM;
#pragma unroll
  for (int k = 0; k < 32; k += 8) t[ty + k][tx] = src[(i0 + ty + k) * D_DIM + o0 + tx];
  __syncthreads();
#pragma unroll
  for (int k = 0; k < 32; k += 8) dst[(o0 + ty + k) * D_DIM + i0 + tx] = t[tx][ty + k];
}

// out[n][o] = sum_i A[n][i]*Wm[o][i]; 32-row tile, thread tile 4x4, XOR-swizzled W in LDS.
__global__ __launch_bounds__(256) void gemm_x(const float* __restrict__ A,
                                              const float* __restrict__ Wm,
                                              float* __restrict__ out) {
  __shared__ float wsw[64 * D_DIM];
  __shared__ float As[32 * 132];
  int tid = threadIdx.x;
  int rowbase = blockIdx.x * 32;
  float4* wsw4 = (float4*)wsw;
  float4* As4 = (float4*)As;
  int lane_o = tid & 31;
  int row0 = (tid >> 5) << 2;
  float acc[4][4] = {};
  {
    const float4* A4 = (const float4*)A;
#pragma unroll
    for (int j = 0; j < 4; ++j) {
      int e4 = tid + j * 256;
      int n = e4 >> 5, i4 = e4 & 31;
      As4[n * 33 + i4] = A4[((size_t)(rowbase + n) << 5) + i4];
    }
  }
  for (int h = 0; h < 2; ++h) {
    const float4* W4 = (const float4*)(Wm + (size_t)(64 * h) * D_DIM);
#pragma unroll
    for (int j = 0; j < 8; ++j) {
      int e4 = tid + j * 256;
      int o = e4 >> 5, i4 = e4 & 31;
      wsw4[(o << 5) + ((i4 ^ o) & 31)] = W4[e4];
    }
    __syncthreads();
#pragma unroll
    for (int i4 = 0; i4 < 32; ++i4) {
      float4 wv[2], av[4];
#pragma unroll
      for (int c = 0; c < 2; ++c) {
        int o = lane_o + 32 * c;
        wv[c] = wsw4[(o << 5) + ((i4 ^ o) & 31)];
      }
#pragma unroll
      for (int r = 0; r < 4; ++r) av[r] = As4[(row0 + r) * 33 + i4];
#pragma unroll
      for (int r = 0; r < 4; ++r)
#pragma unroll
        for (int c = 0; c < 2; ++c)
          acc[r][2 * h + c] += av[r].x * wv[c].x + av[r].y * wv[c].y +
                               av[r].z * wv[c].z + av[r].w * wv[c].w;
    }
    __syncthreads();
  }
#pragma unroll
  for (int r = 0; r < 4; ++r) {
    float* orow = out + (size_t)(rowbase + row0 + r) * D_DIM;
#pragma unroll
    for (int j = 0; j < 4; ++j) orow[lane_o + 32 * j] = acc[r][j];
  }
}

// Fused: A-tile gathered from CSR (agg rows computed on the fly), then @ relT[rl],
// plain store into upd (chunk-local).
__global__ __launch_bounds__(256) void relgemm_fused(
    const float* __restrict__ tail, const float* __restrict__ relT,
    const int* __restrict__ end_e, const int* __restrict__ cnt_e,
    const int* __restrict__ sCol, const float* __restrict__ sW,
    float* __restrict__ upd, int r0) {
  __shared__ float wsw[64 * D_DIM];
  __shared__ float As[32 * 132];
  int tid = threadIdx.x;
  int rl = r0 + blockIdx.y;
  const float* Wm = relT + (size_t)rl * D_DIM * D_DIM;
  int rowbase = blockIdx.x * 32;
  float4* wsw4 = (float4*)wsw;
  float4* As4 = (float4*)As;

  // CSR gather stage: 8 threads per row, each owns 16 floats (4 float4)
  {
    int rloc = tid >> 3, sub = tid & 7;
    int f = rl * B_HEAD + rowbase + rloc;
    int cn = cnt_e[f];
    int s = end_e[f] - cn;
    float4 a0 = {0, 0, 0, 0}, a1 = {0, 0, 0, 0}, a2 = {0, 0, 0, 0}, a3 = {0, 0, 0, 0};
    for (int k = 0; k < cn; ++k) {
      int col = sCol[s + k];
      float w = sW[s + k];
      const float4* t4 = (const float4*)tail + (size_t)col * 32 + sub * 4;
      f4fma(a0, w, t4[0]);
      f4fma(a1, w, t4[1]);
      f4fma(a2, w, t4[2]);
      f4fma(a3, w, t4[3]);
    }
    int b = rloc * 33 + sub * 4;
    As4[b + 0] = a0; As4[b + 1] = a1; As4[b + 2] = a2; As4[b + 3] = a3;
  }

  int lane_o = tid & 31;
  int row0 = (tid >> 5) << 2;
  float acc[4][4] = {};
  for (int h = 0; h < 2; ++h) {
    const float4* W4 = (const float4*)(Wm + (size_t)(64 * h) * D_DIM);
#pragma unroll
    for (int j = 0; j < 8; ++j) {
      int e4 = tid + j * 256;
      int o = e4 >> 5, i4 = e4 & 31;
      wsw4[(o << 5) + ((i4 ^ o) & 31)] = W4[e4];
    }
    __syncthreads();
#pragma unroll
    for (int i4 = 0; i4 < 32; ++i4) {
      float4 wv[2], av[4];
#pragma unroll
      for (int c = 0; c < 2; ++c) {
        int o = lane_o + 32 * c;
        wv[c] = wsw4[(o << 5) + ((i4 ^ o) & 31)];
      }
#pragma unroll
      for (int r = 0; r < 4; ++r) av[r] = As4[(row0 + r) * 33 + i4];
#pragma unroll
      for (int r = 0; r < 4; ++r)
#pragma unroll
        for (int c = 0; c < 2; ++c)
          acc[r][2 * h + c] += av[r].x * wv[c].x + av[r].y * wv[c].y +
                               av[r].z * wv[c].z + av[r].w * wv[c].w;
    }
    __syncthreads();
  }
#pragma unroll
  for (int r = 0; r < 4; ++r) {
    float* orow = upd + ((size_t)blockIdx.y * B_HEAD + rowbase + row0 + r) * D_DIM;
#pragma unroll
    for (int j = 0; j < 4; ++j) orow[lane_o + 32 * j] = acc[r][j];
  }
}

// out[n] (+)= sum of upd rows mapped to entity n (within [f0,f1)), optional relu.
__global__ __launch_bounds__(256) void final_add(const int* __restrict__ end_h,
                                                 const int* __restrict__ cnt_h,
                                                 const int* __restrict__ list,
                                                 const float* __restrict__ upd,
                                                 float* __restrict__ out, int f0,
                                                 int f1, int doRelu) {
  int n = blockIdx.x * 8 + (threadIdx.x >> 5);
  int lane = threadIdx.x & 31;
  if (n >= N_ENT) return;
  float4* o4 = (float4*)out + (size_t)n * 32 + lane;
  float4 v = *o4;
  int c = cnt_h[n];
  int s = end_h[n] - c;
  for (int k = 0; k < c; ++k) {
    int f = list[s + k];
    if (f < f0 || f >= f1) continue;
    const float4* u4 = (const float4*)upd + (size_t)(f - f0) * 32 + lane;
    float4 u = *u4;
    v.x += u.x; v.y += u.y; v.z += u.z; v.w += u.w;
  }
  if (doRelu) {
    v.x = fmaxf(v.x, 0.f); v.y = fmaxf(v.y, 0.f);
    v.z = fmaxf(v.z, 0.f); v.w = fmaxf(v.w, 0.f);
  }
  *o4 = v;
}

extern "C" void kernel_launch(void* const* d_in, const int* in_sizes, int n_in,
                              void* d_out, int out_size, void* d_ws, size_t ws_size,
                              hipStream_t stream) {
  const float* x = (const float*)d_in[0];
  const float* tail = (const float*)d_in[1];
  const float* W = (const float*)d_in[2];
  const float* relW = (const float*)d_in[3];
  const float* ew = (const float*)d_in[4];
  const int* erow = (const int*)d_in[5];
  const int* ecol = (const int*)d_in[6];
  const int* head = (const int*)d_in[7];
  float* out = (float*)d_out;

  // ws layout (16B-aligned chunks):
  char* p = (char*)d_ws;
  float* relT = (float*)p;            p += (size_t)R_REL * D_DIM * D_DIM * 4;
  int* cnt_e = (int*)p;               p += (size_t)R_REL * B_HEAD * 4;
  int* cnt_h = (int*)p;               p += (size_t)NH_PAD * 4;
  int* cur_e = (int*)p;               p += (size_t)R_REL * B_HEAD * 4;   // becomes end_e
  int* cur_h = (int*)p;               p += (size_t)NH_PAD * 4;           // becomes end_h
  int* list_h = (int*)p;              p += (size_t)R_REL * B_HEAD * 4;
  int* sCol = (int*)p;                p += (size_t)R_REL * E_EDGE * 4;
  float* sW = (float*)p;              p += (size_t)R_REL * E_EDGE * 4;
  float* upd = (float*)p;
  size_t fixed = (size_t)(p - (char*)d_ws);
  size_t per_rel = (size_t)B_HEAD * D_DIM * 4;
  size_t avail = (ws_size > fixed) ? ws_size - fixed : 0;
  int chunk = (int)(avail / per_rel);
  if (chunk > R_REL) chunk = R_REL;
  if (chunk < 1) chunk = 1;

  // zero cnt_e + cnt_h (contiguous): (262144 + 100352)/256 = 1416 blocks exact
  zero_counts<<<dim3((R_REL * B_HEAD + NH_PAD) / 256), 256, 0, stream>>>(cnt_e);
  transpose_relW<<<dim3(16, R_REL), 256, 0, stream>>>(relW, relT);

  hist_edges<<<dim3(E_EDGE / 256, R_REL), 256, 0, stream>>>(erow, cnt_e);
  hist_heads<<<dim3(R_REL * B_HEAD / 256), 256, 0, stream>>>(head, cnt_h);
  scan_rel<<<dim3(R_REL), 1024, 0, stream>>>(cnt_e, cur_e);
  scan_heads<<<dim3(1), 1024, 0, stream>>>(cnt_h, cur_h);
  scatter_edges<<<dim3(E_EDGE / 256, R_REL), 256, 0, stream>>>(erow, ecol, ew, cur_e,
                                                               sCol, sW);
  scatter_heads<<<dim3(R_REL * B_HEAD / 256), 256, 0, stream>>>(head, cur_h, list_h);

  gemm_x<<<dim3(N_ENT / 32), 256, 0, stream>>>(x, W, out);

  for (int r0 = 0; r0 < R_REL; r0 += chunk) {
    int c = (R_REL - r0 < chunk) ? (R_REL - r0) : chunk;
    relgemm_fused<<<dim3(B_HEAD / 32, c), 256, 0, stream>>>(tail, relT, cur_e, cnt_e,
                                                            sCol, sW, upd, r0);
    final_add<<<dim3((N_ENT + 7) / 8), 256, 0, stream>>>(
        cur_h, cnt_h, list_h, upd, out, r0 * B_HEAD, (r0 + c) * B_HEAD,
        (r0 + c == R_REL) ? 1 : 0);
  }
}